// Round 10
// baseline (572.628 us; speedup 1.0000x reference)
//
#include <hip/hip_runtime.h>
#include <hip/hip_cooperative_groups.h>
namespace cg = cooperative_groups;

#define N_NODES 8192
#define FDIM 128
#define NEG_SLOPE 0.2f
#define SEG 512                       // per-wave neighbor capacity
#define WRPB 8                        // wh rows per group
#define WH_GROUPS (N_NODES / WRPB)    // 1024 row-groups
#define LDS_FLOATS (64 * 132 + WRPB * 68)  // 8992 floats = 35.1 KB
#define GAT_LDS (4 * SEG * 2 + 12 + 4 * FDIM)  // 4620 floats = 18.5 KB

// float -> bf16 bits, round-to-nearest-even (values are all normal finite)
__device__ __forceinline__ unsigned int f2bf(float f) {
  unsigned int u = __float_as_uint(f);
  return (u + 0x7FFFu + ((u >> 16) & 1u)) >> 16;
}

// non-temporal float4 load: adj is streamed exactly once
__device__ __forceinline__ float4 ntload4(const float4* p) {
  typedef float f4v __attribute__((ext_vector_type(4)));
  f4v v = __builtin_nontemporal_load((const f4v*)p);
  return make_float4(v[0], v[1], v[2], v[3]);
}

// exact wave64 prefix-popcount of ballot mask below this lane (2 VALU ops)
__device__ __forceinline__ int mbcnt64(unsigned long long b) {
  return (int)__builtin_amdgcn_mbcnt_hi(
      (unsigned)(b >> 32), __builtin_amdgcn_mbcnt_lo((unsigned)b, 0u));
}

// ---- phase-1 body: Whb(bf16)=h@W.T, colsum S, s1/s2 for one 8-row group ----
__device__ __forceinline__ void wh_group(
    int grp, const float* __restrict__ h, const float* __restrict__ W,
    const float* __restrict__ a, unsigned int* __restrict__ Whb,
    float* __restrict__ s1, float* __restrict__ s2, float* __restrict__ S,
    float* lds) {
  float* Wt = lds;                 // [64][132] W^T K-half
  float* rowsL = lds + 64 * 132;   // [8][68] h-row halves
  const int t = threadIdx.x;
  const int base = grp * WRPB;
  const int g = t >> 5;            // 8 groups; group g owns row base+g
  const int c4 = (t & 31) * 4;     // 4 output cols per lane
  float acc[4] = {0.f, 0.f, 0.f, 0.f};
#pragma unroll
  for (int h2 = 0; h2 < 2; ++h2) {
    const int k0 = h2 * 64;
    __syncthreads();               // guard Wt/rowsL reuse (prev half/group)
    for (int s = 0; s < 8; ++s) {  // W-half: float4 loads, transposed store
      int idx = t + 256 * s;       // 2048 float4s: 128 o x 16 k-quads
      int o = idx >> 4, kq = (idx & 15) * 4;
      float4 w4 = *(const float4*)&W[o * FDIM + k0 + kq];
      Wt[(kq + 0) * 132 + o] = w4.x;
      Wt[(kq + 1) * 132 + o] = w4.y;
      Wt[(kq + 2) * 132 + o] = w4.z;
      Wt[(kq + 3) * 132 + o] = w4.w;
    }
    if (t < 128) {                 // 8 h-row halves: 128 float4s
      int r = t >> 4, kq = (t & 15) * 4;
      *(float4*)&rowsL[r * 68 + kq] =
          *(const float4*)&h[(size_t)(base + r) * FDIM + k0 + kq];
    }
    __syncthreads();
#pragma unroll 4
    for (int k = 0; k < 64; ++k) {
      float4 wv = *(const float4*)&Wt[k * 132 + c4];  // b128 conflict-free
      float rv = rowsL[g * 68 + k];                   // broadcast
      acc[0] += rv * wv.x; acc[1] += rv * wv.y;
      acc[2] += rv * wv.z; acc[3] += rv * wv.w;
    }
  }
  const int r = base + g;
  unsigned int p0 = f2bf(acc[0]) | (f2bf(acc[1]) << 16);
  unsigned int p1 = f2bf(acc[2]) | (f2bf(acc[3]) << 16);
  *(uint2*)&Whb[(size_t)r * 64 + (c4 >> 1)] = make_uint2(p0, p1);
  {
    float4 a1v = *(const float4*)&a[c4];
    float4 a2v = *(const float4*)&a[FDIM + c4];
    float d1 = acc[0] * a1v.x + acc[1] * a1v.y + acc[2] * a1v.z + acc[3] * a1v.w;
    float d2 = acc[0] * a2v.x + acc[1] * a2v.y + acc[2] * a2v.z + acc[3] * a2v.w;
#pragma unroll
    for (int off = 16; off; off >>= 1) {
      d1 += __shfl_down(d1, off);
      d2 += __shfl_down(d2, off);
    }
    if ((t & 31) == 0) { s1[r] = d1; s2[r] = d2; }
  }
  __syncthreads();
  *(float4*)&Wt[g * FDIM + c4] = make_float4(acc[0], acc[1], acc[2], acc[3]);
  __syncthreads();
  if (t < FDIM) {
    float s = 0.f;
#pragma unroll
    for (int gg = 0; gg < 8; ++gg) s += Wt[gg * FDIM + t];
    atomicAdd(&S[t], s);           // device-scope: XCD-coherent
  }
}

// ---- phase-2 body: per-row softmax + sparse gather (r7 bit-equivalent) ----
__device__ __forceinline__ void gat_row(
    int i, const float* __restrict__ adj, const unsigned int* __restrict__ Whb,
    const float* __restrict__ s1, const float* __restrict__ s2,
    const float* __restrict__ S, float* __restrict__ out, float* lds) {
  const int t = threadIdx.x;
  const int lane = t & 63, wave = t >> 6;
  float2* pairs = (float2*)lds;      // 4*SEG float2 = 4096 floats
  int* counts = (int*)(lds + 4096);  // 4
  float* red = lds + 4100;           // 4: per-wave max
  float* red2 = lds + 4104;          // 4: per-wave exp-sum
  float* fpart = lds + 4108;         // 4*FDIM (16B-aligned: 4108%4==0)
  float2* __restrict__ mypairs = pairs + wave * SEG;

  __syncthreads();  // LDS reuse guard (previous row / phase-1 scratch)
  const float s1i = s1[i];
  const float4* __restrict__ arow = (const float4*)(adj + (size_t)i * N_NODES);

  // scan: two 4-chunk passes, ballot compaction
  int cbase = 0;
#pragma unroll
  for (int half8 = 0; half8 < 2; ++half8) {
    float4 av[4];
#pragma unroll
    for (int it = 0; it < 4; ++it)
      av[it] = ntload4(&arow[(half8 * 4 + it) * 256 + t]);
#pragma unroll
    for (int it = 0; it < 4; ++it) {
      const int j4 = (half8 * 4 + it) * 256 + t;
      float v[4] = {av[it].x, av[it].y, av[it].z, av[it].w};
#pragma unroll
      for (int c = 0; c < 4; ++c) {
        bool pred = (v[c] != 0.f);
        unsigned long long bm = __ballot(pred);
        if (pred) {
          int pos = cbase + mbcnt64(bm);
          if (pos < SEG) ((int*)&mypairs[pos])[1] = j4 * 4 + c;
        }
        cbase += (int)__popcll(bm);
      }
    }
  }
  const int mycnt = cbase < SEG ? cbase : SEG;
  if (lane == 0) counts[wave] = mycnt;

  // e from s2[j] gathers (L1/L2-hot), wave max
  float lmax = -1e30f;
  for (int k = lane; k < mycnt; k += 64) {
    int j = ((const int*)&mypairs[k])[1];
    float e = s1i + s2[j];
    e = e > 0.f ? e : NEG_SLOPE * e;
    mypairs[k].x = e;
    lmax = fmaxf(lmax, e);
  }
  for (int off = 32; off; off >>= 1) lmax = fmaxf(lmax, __shfl_down(lmax, off));
  if (lane == 0) red[wave] = lmax;
  __syncthreads();
  const int cnt = counts[0] + counts[1] + counts[2] + counts[3];
  float m = fmaxf(fmaxf(red[0], red[1]), fmaxf(red[2], red[3]));
  if (cnt < N_NODES) m = fmaxf(m, 0.f);  // adj==0 entries contribute z=0
  const float em = __expf(-m);

  // p = exp(e-m) once per pair, wave sum
  float lsum = 0.f;
  for (int k = lane; k < mycnt; k += 64) {
    float p = __expf(mypairs[k].x - m);
    mypairs[k].x = p;
    lsum += p;
  }
  for (int off = 32; off; off >>= 1) lsum += __shfl_down(lsum, off);
  if (lane == 0) red2[wave] = lsum;
  // no barrier: gather below reads only this wave's own segment

  // gather: half-wave per pair, bf16 rows, 4-deep unroll
  const int half = lane >> 5, lq = lane & 31;
  const uint2* __restrict__ Whb2 = (const uint2*)Whb;
  float ax = 0.f, ay = 0.f, az = 0.f, aw = 0.f;
  const int nit = (mycnt + 1) >> 1;
  int it = 0;
  for (; it + 3 < nit; it += 4) {
#pragma unroll
    for (int c = 0; c < 4; ++c) {
      int p = 2 * (it + c) + half;
      bool ok = p < mycnt;
      float2 pr = mypairs[ok ? p : 0];
      int j = ((const int*)&pr)[1];
      uint2 d = Whb2[((size_t)j << 5) + lq];
      float w = ok ? pr.x - em : 0.f;
      ax += w * __uint_as_float(d.x << 16);
      ay += w * __uint_as_float(d.x & 0xffff0000u);
      az += w * __uint_as_float(d.y << 16);
      aw += w * __uint_as_float(d.y & 0xffff0000u);
    }
  }
  for (; it < nit; ++it) {
    int p = 2 * it + half;
    bool ok = p < mycnt;
    float2 pr = mypairs[ok ? p : 0];
    int j = ((const int*)&pr)[1];
    uint2 d = Whb2[((size_t)j << 5) + lq];
    float w = ok ? pr.x - em : 0.f;
    ax += w * __uint_as_float(d.x << 16);
    ay += w * __uint_as_float(d.x & 0xffff0000u);
    az += w * __uint_as_float(d.y << 16);
    aw += w * __uint_as_float(d.y & 0xffff0000u);
  }
  ax += __shfl_down(ax, 32);
  ay += __shfl_down(ay, 32);
  az += __shfl_down(az, 32);
  aw += __shfl_down(aw, 32);
  if (lane < 32)
    *(float4*)&fpart[wave * FDIM + 4 * lq] = make_float4(ax, ay, az, aw);
  __syncthreads();
  if (t < FDIM) {
    float l = red2[0] + red2[1] + red2[2] + red2[3]
              + (float)(N_NODES - cnt) * em;
    float o = (fpart[0 * FDIM + t] + fpart[1 * FDIM + t] +
               fpart[2 * FDIM + t] + fpart[3 * FDIM + t] + em * S[t]) / l;
    out[(size_t)i * FDIM + t] = o;
  }
}

// ---------------- mono cooperative kernel (grid-size agnostic) ----------------
__global__ __launch_bounds__(256, 4) void gatv2_mono_kernel(
    const float* __restrict__ h, const float* __restrict__ adj,
    const float* __restrict__ W, const float* __restrict__ a,
    unsigned int* __restrict__ Whb, float* __restrict__ s1,
    float* __restrict__ s2, float* __restrict__ S, float* __restrict__ out) {
  cg::grid_group grid = cg::this_grid();
  __shared__ float lds[LDS_FLOATS];
  const int b = blockIdx.x, nb = gridDim.x;
  if (b == 0 && threadIdx.x < FDIM) S[threadIdx.x] = 0.f;
  grid.sync();
  for (int grp = b; grp < WH_GROUPS; grp += nb)
    wh_group(grp, h, W, a, Whb, s1, s2, S, lds);
  grid.sync();
  for (int i = b; i < N_NODES; i += nb)
    gat_row(i, adj, Whb, s1, s2, S, out, lds);
}

// ---------------- fallback standalone kernels (r7-equivalent path) ----------
__global__ __launch_bounds__(256) void wh_kernel(
    const float* __restrict__ h, const float* __restrict__ W,
    const float* __restrict__ a, unsigned int* __restrict__ Whb,
    float* __restrict__ s1, float* __restrict__ s2, float* __restrict__ S) {
  __shared__ float lds[LDS_FLOATS];
  for (int grp = blockIdx.x; grp < WH_GROUPS; grp += gridDim.x)
    wh_group(grp, h, W, a, Whb, s1, s2, S, lds);
}

__global__ __launch_bounds__(256, 8) void gat_kernel(
    const float* __restrict__ adj, const unsigned int* __restrict__ Whb,
    const float* __restrict__ s1, const float* __restrict__ s2,
    const float* __restrict__ S, float* __restrict__ out) {
  __shared__ float lds[GAT_LDS];
  gat_row(blockIdx.x, adj, Whb, s1, s2, S, out, lds);
}

extern "C" void kernel_launch(void* const* d_in, const int* in_sizes, int n_in,
                              void* d_out, int out_size, void* d_ws, size_t ws_size,
                              hipStream_t stream) {
  const float* h   = (const float*)d_in[0];
  const float* adj = (const float*)d_in[1];
  const float* W   = (const float*)d_in[2];
  const float* a   = (const float*)d_in[3];
  float* out = (float*)d_out;
  // workspace layout: Whb(bf16, N*64 uints = 2 MB) | s1[N] | s2[N] | S[F]
  unsigned int* Whb = (unsigned int*)d_ws;
  float* s1 = (float*)(Whb + (size_t)N_NODES * 64);
  float* s2 = s1 + N_NODES;
  float* S  = s2 + N_NODES;

  // one-time capability probe (host queries only — capture-safe, no stream ops)
  static int coop_nblk = -2;  // -2 uninit, -1 unavailable, >0 grid size
  if (coop_nblk == -2) {
    int dev = 0, coop = 0, cus = 0, mab = 0;
    hipGetDevice(&dev);
    hipDeviceGetAttribute(&coop, hipDeviceAttributeCooperativeLaunch, dev);
    hipDeviceGetAttribute(&cus, hipDeviceAttributeMultiprocessorCount, dev);
    hipError_t e = hipOccupancyMaxActiveBlocksPerMultiprocessor(
        &mab, gatv2_mono_kernel, 256, 0);
    if (coop && e == hipSuccess && mab >= 1 && cus >= 1) {
      long cap = (long)mab * cus;            // never exceed runtime's capacity
      coop_nblk = (int)(cap < 1024 ? cap : 1024);
    } else {
      coop_nblk = -1;
    }
  }

  if (coop_nblk > 0) {
    void* args[] = {(void*)&h, (void*)&adj, (void*)&W, (void*)&a,
                    (void*)&Whb, (void*)&s1, (void*)&s2, (void*)&S,
                    (void*)&out};
    hipError_t err = hipLaunchCooperativeKernel(
        gatv2_mono_kernel, dim3(coop_nblk), dim3(256), args, 0u, stream);
    if (err == hipSuccess) return;
    coop_nblk = -1;  // disable for future calls; fall through to safe path
  }

  // fallback: proven 3-dispatch path (= r7 behavior, ~404 us)
  hipMemsetAsync(S, 0, FDIM * sizeof(float), stream);
  hipLaunchKernelGGL(wh_kernel, dim3(WH_GROUPS), dim3(256), 0, stream,
                     h, W, a, Whb, s1, s2, S);
  hipLaunchKernelGGL(gat_kernel, dim3(N_NODES), dim3(256), 0, stream,
                     adj, Whb, s1, s2, S, out);
}